// Round 1
// baseline (556.675 us; speedup 1.0000x reference)
//
#include <hip/hip_runtime.h>
#include <cstdint>
#include <cstddef>

// ---------------- problem constants ----------------
#define Bn   16
#define Cn   256
#define Nn   4096      // 16^3 spatial
#define Ln   77
#define LPn  80        // padded L rows for k_t (scores N-dim, 5 tiles of 16)
#define LKn  96        // padded L for PV K-dim (3 k-steps of 32)
#define CTXn 768
#define Gn   32

typedef unsigned short u16;
typedef unsigned int   u32;
using frag8 = __attribute__((ext_vector_type(8))) short;   // 8 x bf16 (4 VGPR)
using f32x4 = __attribute__((ext_vector_type(4))) float;
using u16x4 = __attribute__((ext_vector_type(4))) u16;

__device__ __forceinline__ float b2f(u16 b) {
    union { u32 u; float f; } v; v.u = ((u32)b) << 16; return v.f;
}
__device__ __forceinline__ u16 f2b(float f) {  // RNE f32->bf16
    union { float f; u32 u; } v; v.f = f;
    u32 u = v.u;
    return (u16)((u + 0x7fffu + ((u >> 16) & 1u)) >> 16);
}

// ---------------- ws layout (bytes) ----------------
// R1 [0, 32M):  xt (bf16 [B][N][C])  -> later reused as ht (bf16 [B][N][C])
// R2 [32M,64M): q  (bf16 [B][N][C])  -> later reused as t  (bf16 [B][C][N])
static const size_t OFF_XT  = 0;
static const size_t OFF_HT  = 0;                    // alias: xt dead after qgemm
static const size_t OFF_Q   = 33554432;
static const size_t OFF_T   = 33554432;             // alias: q dead after attn
static const size_t OFF_KT  = 67108864;             // bf16 [B][80][256]
static const size_t OFF_V   = 67764224;             // bf16 [B][256][96]
static const size_t OFF_QWB = 68550656;             // bf16 [256][256]
static const size_t OFF_OWB = 68681728;             // bf16 [256][256]
static const size_t OFF_GS  = 68812800;             // f32 [B][32]
static const size_t OFF_GQ  = 68814848;             // f32 [B][32]

// ---------------- 1: weight cast ----------------
__global__ void k_prep_w(const float* __restrict__ qw, const float* __restrict__ ow,
                         u16* __restrict__ qwb, u16* __restrict__ owb) {
    int i = blockIdx.x * 256 + threadIdx.x;   // 65536 total
    qwb[i] = f2b(qw[i]);
    owb[i] = f2b(ow[i]);
}

// ---------------- 2: transpose+cast x[b][c][n] -> xt[b][n][c] ----------------
__global__ void k_xt(const float* __restrict__ x, u16* __restrict__ xt) {
    int b = blockIdx.z;
    int c0 = blockIdx.y * 64, n0 = blockIdx.x * 64;
    __shared__ float tile[64][65];   // +1 pad: conflict-free column reads
    int tid = threadIdx.x;
    int tr = tid >> 4, tc4 = (tid & 15) * 4;
#pragma unroll
    for (int i = 0; i < 4; ++i) {
        int cc = tr + i * 16;
        f32x4 vv = *(const f32x4*)(x + ((size_t)(b * Cn + c0 + cc)) * Nn + n0 + tc4);
#pragma unroll
        for (int j = 0; j < 4; ++j) tile[cc][tc4 + j] = vv[j];
    }
    __syncthreads();
#pragma unroll
    for (int i = 0; i < 4; ++i) {
        int nn = tr + i * 16;
        u16x4 pk;
#pragma unroll
        for (int j = 0; j < 4; ++j) pk[j] = f2b(tile[tc4 + j][nn]);
        *(u16x4*)(xt + ((size_t)(b * Nn + n0 + nn)) * Cn + c0 + tc4) = pk;
    }
}

// ---------------- 3: k/v projections ----------------
// k_t[b][l][c] = sum_d context[b,l,d]*k_w[c,d]  (rows l=77..79 zero)
// v  [b][c][l] = sum_d context[b,l,d]*v_w[c,d]  (l=77..95 zero)
__global__ void k_kv(const float* __restrict__ ctx, const float* __restrict__ kw,
                     const float* __restrict__ vw, u16* __restrict__ kt,
                     u16* __restrict__ v) {
    int l = blockIdx.x, b = blockIdx.y;
    int c = threadIdx.x;
    if (l < Ln) {
        __shared__ float cs[CTXn];
        for (int d = threadIdx.x; d < CTXn; d += 256)
            cs[d] = ctx[((size_t)(b * Ln + l)) * CTXn + d];
        __syncthreads();
        float ka = 0.f, va = 0.f;
        const f32x4* kr = (const f32x4*)(kw + (size_t)c * CTXn);
        const f32x4* vr = (const f32x4*)(vw + (size_t)c * CTXn);
        const f32x4* cr = (const f32x4*)cs;
        for (int d4 = 0; d4 < CTXn / 4; ++d4) {
            f32x4 cv = cr[d4], kv4 = kr[d4], vv4 = vr[d4];
#pragma unroll
            for (int j = 0; j < 4; ++j) { ka += cv[j] * kv4[j]; va += cv[j] * vv4[j]; }
        }
        kt[((size_t)(b * LPn + l)) * Cn + c] = f2b(ka);
        v[((size_t)(b * Cn + c)) * LKn + l] = f2b(va);
    } else {
        kt[((size_t)(b * LPn + l)) * Cn + c] = 0;       // zero pad rows 77..79
        if (l == Ln) {
            for (int ll = Ln; ll < LKn; ++ll)
                v[((size_t)(b * Cn + c)) * LKn + ll] = 0; // zero v pad 77..95
        }
    }
}

// ---------------- 4: q projection (MFMA), writes q transposed [b][n][c] ----------------
__launch_bounds__(256)
__global__ void k_qgemm(const u16* __restrict__ qwb, const u16* __restrict__ xt,
                        const float* __restrict__ qb, u16* __restrict__ qt) {
    int nb = blockIdx.x, b = blockIdx.y;
    int tid = threadIdx.x;
    int wave = tid >> 6, lane = tid & 63;
    int l15 = lane & 15, q4 = lane >> 4;
    int n0 = nb * 64;
    const u16* xb = xt + ((size_t)(b * Nn + n0)) * Cn;
    f32x4 acc[4][4];
#pragma unroll
    for (int mt = 0; mt < 4; ++mt)
#pragma unroll
        for (int nt = 0; nt < 4; ++nt) acc[mt][nt] = (f32x4){0.f, 0.f, 0.f, 0.f};

    for (int ks = 0; ks < 8; ++ks) {
        int kk = ks * 32 + 8 * q4;
        frag8 a[4], bb[4];
#pragma unroll
        for (int mt = 0; mt < 4; ++mt)
            a[mt] = *(const frag8*)(qwb + (size_t)(wave * 64 + mt * 16 + l15) * Cn + kk);
#pragma unroll
        for (int nt = 0; nt < 4; ++nt)
            bb[nt] = *(const frag8*)(xb + (size_t)(nt * 16 + l15) * Cn + kk);
#pragma unroll
        for (int mt = 0; mt < 4; ++mt)
#pragma unroll
            for (int nt = 0; nt < 4; ++nt)
                acc[mt][nt] = __builtin_amdgcn_mfma_f32_16x16x32_bf16(a[mt], bb[nt], acc[mt][nt], 0, 0, 0);
    }
    u16* qtb = qt + ((size_t)(b * Nn + n0)) * Cn;
#pragma unroll
    for (int mt = 0; mt < 4; ++mt) {
        int obase = wave * 64 + mt * 16 + q4 * 4;
        float b0 = qb[obase + 0], b1 = qb[obase + 1], b2 = qb[obase + 2], b3 = qb[obase + 3];
#pragma unroll
        for (int nt = 0; nt < 4; ++nt) {
            int n = nt * 16 + l15;
            u16x4 pk;
            pk[0] = f2b(acc[mt][nt][0] + b0);
            pk[1] = f2b(acc[mt][nt][1] + b1);
            pk[2] = f2b(acc[mt][nt][2] + b2);
            pk[3] = f2b(acc[mt][nt][3] + b3);
            *(u16x4*)(qtb + (size_t)n * Cn + obase) = pk;
        }
    }
}

// ---------------- 5: fused attention (1 wave / block, NT=16 rows) ----------------
// scores^T[l][n] = sum_c k_t[l][c]*q[n][c]   (swapped QK^T: softmax needs 2 shfls)
// h_t[n][c]      = sum_l w[n][l]*v[c][l]
__launch_bounds__(64)
__global__ void k_attn(const u16* __restrict__ kt, const u16* __restrict__ v,
                       const u16* __restrict__ qt, u16* __restrict__ ht) {
    int nb = blockIdx.x, b = blockIdx.y;
    int lane = threadIdx.x;
    int l15 = lane & 15, q4 = lane >> 4;
    const u16* ktb = kt + (size_t)b * LPn * Cn;
    const u16* qtb = qt + ((size_t)(b * Nn + nb * 16)) * Cn;

    f32x4 s[5];
#pragma unroll
    for (int mt = 0; mt < 5; ++mt) s[mt] = (f32x4){0.f, 0.f, 0.f, 0.f};
#pragma unroll
    for (int ks = 0; ks < 8; ++ks) {
        int kk = ks * 32 + 8 * q4;
        frag8 bq = *(const frag8*)(qtb + (size_t)l15 * Cn + kk);
#pragma unroll
        for (int mt = 0; mt < 5; ++mt) {
            frag8 ak = *(const frag8*)(ktb + (size_t)(mt * 16 + l15) * Cn + kk);
            s[mt] = __builtin_amdgcn_mfma_f32_16x16x32_bf16(ak, bq, s[mt], 0, 0, 0);
        }
    }
    // lane holds: n = l15 (fixed), l = mt*16 + q4*4 + r. Softmax over l per n.
    float m = -3e38f;
#pragma unroll
    for (int mt = 0; mt < 5; ++mt)
#pragma unroll
        for (int r = 0; r < 4; ++r) {
            int l = mt * 16 + q4 * 4 + r;
            if (l < Ln) m = fmaxf(m, s[mt][r]);
        }
    m = fmaxf(m, __shfl_xor(m, 16));
    m = fmaxf(m, __shfl_xor(m, 32));
    float p[5][4];
    float sum = 0.f;
#pragma unroll
    for (int mt = 0; mt < 5; ++mt)
#pragma unroll
        for (int r = 0; r < 4; ++r) {
            int l = mt * 16 + q4 * 4 + r;
            float e = (l < Ln) ? __expf(s[mt][r] - m) : 0.f;
            p[mt][r] = e;
            sum += e;
        }
    sum += __shfl_xor(sum, 16);
    sum += __shfl_xor(sum, 32);
    float inv = 1.f / sum;

    __shared__ u16 w_lds[16][104];   // [n][l padded to 96 + 8 align pad]
    u32* wz = (u32*)&w_lds[0][0];    // 16*104/2 = 832 words = 13*64
#pragma unroll
    for (int i = 0; i < 13; ++i) wz[lane + i * 64] = 0;
    __syncthreads();
#pragma unroll
    for (int mt = 0; mt < 5; ++mt)
#pragma unroll
        for (int r = 0; r < 4; ++r) {
            int l = mt * 16 + q4 * 4 + r;
            if (l < Ln) w_lds[l15][l] = f2b(p[mt][r] * inv);
        }
    __syncthreads();

    frag8 aw[3];
#pragma unroll
    for (int ks = 0; ks < 3; ++ks)
        aw[ks] = *(const frag8*)(&w_lds[l15][ks * 32 + 8 * q4]);
    const u16* vb = v + (size_t)b * Cn * LKn;
    u16* hb = ht + ((size_t)(b * Nn + nb * 16)) * Cn;
#pragma unroll
    for (int ct = 0; ct < 16; ++ct) {
        f32x4 h = (f32x4){0.f, 0.f, 0.f, 0.f};
#pragma unroll
        for (int ks = 0; ks < 3; ++ks) {
            frag8 bv = *(const frag8*)(vb + (size_t)(ct * 16 + l15) * LKn + ks * 32 + 8 * q4);
            h = __builtin_amdgcn_mfma_f32_16x16x32_bf16(aw[ks], bv, h, 0, 0, 0);
        }
#pragma unroll
        for (int r = 0; r < 4; ++r)
            hb[(size_t)(q4 * 4 + r) * Cn + ct * 16 + l15] = f2b(h[r]);
    }
}

// ---------------- 6: out projection + bias + residual -> t (bf16 [b][c][n]) ----------------
__launch_bounds__(256)
__global__ void k_outproj(const u16* __restrict__ owb, const u16* __restrict__ ht,
                          const float* __restrict__ ob, const float* __restrict__ x,
                          u16* __restrict__ t) {
    int nb = blockIdx.x, b = blockIdx.y;
    int tid = threadIdx.x;
    int wave = tid >> 6, lane = tid & 63;
    int l15 = lane & 15, q4 = lane >> 4;
    int n0 = nb * 64;
    const u16* hb = ht + ((size_t)(b * Nn + n0)) * Cn;
    f32x4 acc[4][4];
#pragma unroll
    for (int mt = 0; mt < 4; ++mt)
#pragma unroll
        for (int nt = 0; nt < 4; ++nt) acc[mt][nt] = (f32x4){0.f, 0.f, 0.f, 0.f};

    for (int ks = 0; ks < 8; ++ks) {
        int kk = ks * 32 + 8 * q4;
        frag8 a[4], bb[4];
#pragma unroll
        for (int mt = 0; mt < 4; ++mt)
            a[mt] = *(const frag8*)(owb + (size_t)(wave * 64 + mt * 16 + l15) * Cn + kk);
#pragma unroll
        for (int nt = 0; nt < 4; ++nt)
            bb[nt] = *(const frag8*)(hb + (size_t)(nt * 16 + l15) * Cn + kk);
#pragma unroll
        for (int mt = 0; mt < 4; ++mt)
#pragma unroll
            for (int nt = 0; nt < 4; ++nt)
                acc[mt][nt] = __builtin_amdgcn_mfma_f32_16x16x32_bf16(a[mt], bb[nt], acc[mt][nt], 0, 0, 0);
    }
#pragma unroll
    for (int mt = 0; mt < 4; ++mt) {
        int obase = wave * 64 + mt * 16 + q4 * 4;
#pragma unroll
        for (int r = 0; r < 4; ++r) {
            int o = obase + r;
            float bias = ob[o];
            size_t rowbase = ((size_t)(b * Cn + o)) * Nn + n0;
#pragma unroll
            for (int nt = 0; nt < 4; ++nt) {
                int n = nt * 16 + l15;
                t[rowbase + n] = f2b(acc[mt][nt][r] + bias + x[rowbase + n]);
            }
        }
    }
}

// ---------------- 7: GroupNorm partial sums ----------------
__global__ void k_gnpart(const u16* __restrict__ t, float* __restrict__ gsum,
                         float* __restrict__ gsq) {
    int nc = blockIdx.x, g = blockIdx.y, b = blockIdx.z;
    int tid = threadIdx.x;
    float s = 0.f, q = 0.f;
#pragma unroll
    for (int cc = 0; cc < 8; ++cc) {
        size_t base = ((size_t)(b * Cn + g * 8 + cc)) * Nn + nc * 512;
        u32 u = *(const u32*)(t + base + tid * 2);
        float v0 = __uint_as_float(u << 16);
        float v1 = __uint_as_float(u & 0xffff0000u);
        s += v0 + v1;
        q += v0 * v0 + v1 * v1;
    }
    for (int off = 32; off > 0; off >>= 1) {
        s += __shfl_down(s, off);
        q += __shfl_down(q, off);
    }
    __shared__ float rs[4], rq[4];
    int w = tid >> 6;
    if ((tid & 63) == 0) { rs[w] = s; rq[w] = q; }
    __syncthreads();
    if (tid == 0) {
        atomicAdd(&gsum[b * Gn + g], rs[0] + rs[1] + rs[2] + rs[3]);
        atomicAdd(&gsq[b * Gn + g], rq[0] + rq[1] + rq[2] + rq[3]);
    }
}

// ---------------- 8: GroupNorm apply + Swish ----------------
__global__ void k_gnapply(const u16* __restrict__ t, const float* __restrict__ gsum,
                          const float* __restrict__ gsq, const float* __restrict__ gamma,
                          const float* __restrict__ beta, float* __restrict__ out) {
    int i = (blockIdx.x * 256 + threadIdx.x) * 4;
    int b = i >> 20;            // / (Cn*Nn)
    int rem = i & 1048575;
    int c = rem >> 12;          // / Nn
    int g = c >> 3;
    float mean = gsum[b * Gn + g] * (1.0f / 32768.f);
    float var = gsq[b * Gn + g] * (1.0f / 32768.f) - mean * mean;
    float rstd = rsqrtf(var + 1e-5f);
    float ga = gamma[c], be = beta[c];
    u16x4 tv = *(const u16x4*)(t + i);
    f32x4 o;
#pragma unroll
    for (int j = 0; j < 4; ++j) {
        float hv = (b2f(tv[j]) - mean) * rstd * ga + be;
        o[j] = hv / (1.f + __expf(-hv));
    }
    *(f32x4*)(out + i) = o;
}

// ---------------- launcher ----------------
extern "C" void kernel_launch(void* const* d_in, const int* in_sizes, int n_in,
                              void* d_out, int out_size, void* d_ws, size_t ws_size,
                              hipStream_t stream) {
    (void)in_sizes; (void)n_in; (void)out_size; (void)ws_size;
    const float* x     = (const float*)d_in[0];
    const float* ctx   = (const float*)d_in[1];
    const float* qw    = (const float*)d_in[2];
    const float* qb    = (const float*)d_in[3];
    const float* kw    = (const float*)d_in[4];
    const float* vw    = (const float*)d_in[5];
    const float* ow    = (const float*)d_in[6];
    const float* ob    = (const float*)d_in[7];
    const float* gamma = (const float*)d_in[8];
    const float* beta  = (const float*)d_in[9];
    float* out = (float*)d_out;
    char* ws = (char*)d_ws;

    u16* xt  = (u16*)(ws + OFF_XT);
    u16* ht  = (u16*)(ws + OFF_HT);
    u16* qt  = (u16*)(ws + OFF_Q);
    u16* t   = (u16*)(ws + OFF_T);
    u16* kt  = (u16*)(ws + OFF_KT);
    u16* v   = (u16*)(ws + OFF_V);
    u16* qwb = (u16*)(ws + OFF_QWB);
    u16* owb = (u16*)(ws + OFF_OWB);
    float* gsum = (float*)(ws + OFF_GS);
    float* gsq  = (float*)(ws + OFF_GQ);

    hipMemsetAsync(ws + OFF_GS, 0, 4096, stream);   // gsum+gsq

    k_prep_w<<<256, 256, 0, stream>>>(qw, ow, qwb, owb);
    k_xt<<<dim3(64, 4, 16), 256, 0, stream>>>(x, xt);
    k_kv<<<dim3(LPn, Bn), 256, 0, stream>>>(ctx, kw, vw, kt, v);
    k_qgemm<<<dim3(64, Bn), 256, 0, stream>>>(qwb, xt, qb, qt);
    k_attn<<<dim3(256, Bn), 64, 0, stream>>>(kt, v, qt, ht);
    k_outproj<<<dim3(64, Bn), 256, 0, stream>>>(owb, ht, ob, x, t);
    k_gnpart<<<dim3(8, Gn, Bn), 256, 0, stream>>>(t, gsum, gsq);
    k_gnapply<<<16384, 256, 0, stream>>>(t, gsum, gsq, gamma, beta, out);
}

// Round 2
// 229.577 us; speedup vs baseline: 2.4248x; 2.4248x over previous
//
#include <hip/hip_runtime.h>
#include <cstdint>
#include <cstddef>

// ---------------- problem constants ----------------
#define Bn   16
#define Cn   256
#define Nn   4096      // 16^3 spatial
#define Ln   77
#define LPn  80        // padded L rows for k_t (scores N-dim, 5 tiles of 16)
#define LKn  96        // padded L for PV K-dim (3 k-steps of 32)
#define CTXn 768
#define Gn   32

typedef unsigned short u16;
typedef unsigned int   u32;
using frag8 = __attribute__((ext_vector_type(8))) short;   // 8 x bf16 (4 VGPR)
using f32x4 = __attribute__((ext_vector_type(4))) float;
using u16x4 = __attribute__((ext_vector_type(4))) u16;

__device__ __forceinline__ float b2f(u16 b) {
    union { u32 u; float f; } v; v.u = ((u32)b) << 16; return v.f;
}
__device__ __forceinline__ u16 f2b(float f) {  // RNE f32->bf16
    union { float f; u32 u; } v; v.f = f;
    u32 u = v.u;
    return (u16)((u + 0x7fffu + ((u >> 16) & 1u)) >> 16);
}
__device__ __forceinline__ u16x4 cast4(f32x4 s) {
    u16x4 p; p[0] = f2b(s[0]); p[1] = f2b(s[1]); p[2] = f2b(s[2]); p[3] = f2b(s[3]);
    return p;
}

// ---------------- ws layout (bytes) ----------------
// R1 [0, 32M):  xt (bf16 [B][N][C])  -> later reused as ht (bf16 [B][N][C])
// R2 [32M,64M): ctxb/kwb/vwb (dead after k_kv) -> q (bf16 [B][N][C]) -> t (bf16 [B][C][N])
static const size_t OFF_XT  = 0;
static const size_t OFF_HT  = 0;                    // alias: xt dead after qgemm
static const size_t OFF_Q   = 33554432;
static const size_t OFF_T   = 33554432;             // alias: q dead after attn
static const size_t OFF_CTXB = 33554432;            // bf16 [16][80][768] = 1,966,080 B (dead before qgemm)
static const size_t OFF_KWB  = 35520512;            // bf16 [256][768] = 393,216 B
static const size_t OFF_VWB  = 35913728;            // bf16 [256][768]
static const size_t OFF_KT  = 67108864;             // bf16 [B][80][256]
static const size_t OFF_V   = 67764224;             // bf16 [B][256][96]
static const size_t OFF_QWB = 68550656;             // bf16 [256][256]
static const size_t OFF_OWB = 68681728;             // bf16 [256][256]
static const size_t OFF_GS  = 68812800;             // f32 [B][32]
static const size_t OFF_GQ  = 68814848;             // f32 [B][32]

// ---------------- 1: cast everything to bf16 (vectorized, one pass) ----------------
// segments in x4 units: qw 16384 | ow 16384 | kw 49152 | vw 49152 | ctxb 245760 (pad rows zero)
__global__ void k_prep(const float* __restrict__ qw, const float* __restrict__ ow,
                       const float* __restrict__ kw, const float* __restrict__ vw,
                       const float* __restrict__ ctx,
                       u16* __restrict__ qwb, u16* __restrict__ owb,
                       u16* __restrict__ kwb, u16* __restrict__ vwb,
                       u16* __restrict__ ctxb) {
    int i = blockIdx.x * 256 + threadIdx.x;        // 376832 total
    if (i < 16384) {
        *(u16x4*)(qwb + i * 4) = cast4(*(const f32x4*)(qw + i * 4));
    } else if (i < 32768) {
        int j = i - 16384;
        *(u16x4*)(owb + j * 4) = cast4(*(const f32x4*)(ow + j * 4));
    } else if (i < 81920) {
        int j = i - 32768;
        *(u16x4*)(kwb + j * 4) = cast4(*(const f32x4*)(kw + j * 4));
    } else if (i < 131072) {
        int j = i - 81920;
        *(u16x4*)(vwb + j * 4) = cast4(*(const f32x4*)(vw + j * 4));
    } else {
        int j = i - 131072;                        // 0..245759
        int e = j * 4;
        int row = e / CTXn;                        // b*80 + l
        int d = e - row * CTXn;
        int b = row / LPn, l = row - b * LPn;
        u16x4 pk;
        if (l < Ln) {
            pk = cast4(*(const f32x4*)(ctx + ((size_t)(b * Ln + l)) * CTXn + d));
        } else {
            pk[0] = 0; pk[1] = 0; pk[2] = 0; pk[3] = 0;
        }
        *(u16x4*)(ctxb + e) = pk;
    }
}

// ---------------- 2: transpose+cast x[b][c][n] -> xt[b][n][c] ----------------
__global__ void k_xt(const float* __restrict__ x, u16* __restrict__ xt) {
    int b = blockIdx.z;
    int c0 = blockIdx.y * 64, n0 = blockIdx.x * 64;
    __shared__ float tile[64][65];   // +1 pad: conflict-free column reads
    int tid = threadIdx.x;
    int tr = tid >> 4, tc4 = (tid & 15) * 4;
#pragma unroll
    for (int i = 0; i < 4; ++i) {
        int cc = tr + i * 16;
        f32x4 vv = *(const f32x4*)(x + ((size_t)(b * Cn + c0 + cc)) * Nn + n0 + tc4);
#pragma unroll
        for (int j = 0; j < 4; ++j) tile[cc][tc4 + j] = vv[j];
    }
    __syncthreads();
#pragma unroll
    for (int i = 0; i < 4; ++i) {
        int nn = tr + i * 16;
        u16x4 pk;
#pragma unroll
        for (int j = 0; j < 4; ++j) pk[j] = f2b(tile[tc4 + j][nn]);
        *(u16x4*)(xt + ((size_t)(b * Nn + n0 + nn)) * Cn + c0 + tc4) = pk;
    }
}

// ---------------- 3: k/v projections via MFMA ----------------
// kt[b][l][c] = sum_d ctx[b,l,d]*k_w[c,d]   (D = mfma(kw_frag, ctx_frag): row=c, col=l)
// v [b][c][l] = sum_d ctx[b,l,d]*v_w[c,d]   (D = mfma(ctx_frag, vw_frag): row=l, col=c)
__launch_bounds__(256)
__global__ void k_kv(const u16* __restrict__ kwb, const u16* __restrict__ vwb,
                     const u16* __restrict__ ctxb, u16* __restrict__ kt,
                     u16* __restrict__ v) {
    int b = blockIdx.y;
    int tid = threadIdx.x;
    int wave = tid >> 6, lane = tid & 63;
    int l15 = lane & 15, q4 = lane >> 4;
    int c0 = blockIdx.x * 64 + wave * 16;
    const u16* cb = ctxb + (size_t)b * LPn * CTXn;

    f32x4 ak[5], av[5];
#pragma unroll
    for (int lt = 0; lt < 5; ++lt) {
        ak[lt] = (f32x4){0.f, 0.f, 0.f, 0.f};
        av[lt] = (f32x4){0.f, 0.f, 0.f, 0.f};
    }
    for (int ks = 0; ks < CTXn / 32; ++ks) {
        int kk = ks * 32 + 8 * q4;
        frag8 fk = *(const frag8*)(kwb + (size_t)(c0 + l15) * CTXn + kk);
        frag8 fv = *(const frag8*)(vwb + (size_t)(c0 + l15) * CTXn + kk);
#pragma unroll
        for (int lt = 0; lt < 5; ++lt) {
            frag8 fc = *(const frag8*)(cb + (size_t)(lt * 16 + l15) * CTXn + kk);
            ak[lt] = __builtin_amdgcn_mfma_f32_16x16x32_bf16(fk, fc, ak[lt], 0, 0, 0);
            av[lt] = __builtin_amdgcn_mfma_f32_16x16x32_bf16(fc, fv, av[lt], 0, 0, 0);
        }
    }
#pragma unroll
    for (int lt = 0; lt < 5; ++lt) {
        // kt: row=c (4 consecutive), col=l
        *(u16x4*)(kt + ((size_t)(b * LPn + lt * 16 + l15)) * Cn + c0 + q4 * 4) = cast4(ak[lt]);
        // v: row=l (4 consecutive), col=c
        *(u16x4*)(v + ((size_t)(b * Cn + c0 + l15)) * LKn + lt * 16 + q4 * 4) = cast4(av[lt]);
    }
    // zero v pad l = 80..95 for this wave's c-range
    u16x4 z; z[0] = 0; z[1] = 0; z[2] = 0; z[3] = 0;
    *(u16x4*)(v + ((size_t)(b * Cn + c0 + l15)) * LKn + 80 + q4 * 4) = z;
}

// ---------------- 4: q projection (MFMA), writes q transposed [b][n][c] ----------------
__launch_bounds__(256)
__global__ void k_qgemm(const u16* __restrict__ qwb, const u16* __restrict__ xt,
                        const float* __restrict__ qb, u16* __restrict__ qt) {
    int nb = blockIdx.x, b = blockIdx.y;
    int tid = threadIdx.x;
    int wave = tid >> 6, lane = tid & 63;
    int l15 = lane & 15, q4 = lane >> 4;
    int n0 = nb * 64;
    const u16* xb = xt + ((size_t)(b * Nn + n0)) * Cn;
    f32x4 acc[4][4];
#pragma unroll
    for (int mt = 0; mt < 4; ++mt)
#pragma unroll
        for (int nt = 0; nt < 4; ++nt) acc[mt][nt] = (f32x4){0.f, 0.f, 0.f, 0.f};

    for (int ks = 0; ks < 8; ++ks) {
        int kk = ks * 32 + 8 * q4;
        frag8 a[4], bb[4];
#pragma unroll
        for (int mt = 0; mt < 4; ++mt)
            a[mt] = *(const frag8*)(qwb + (size_t)(wave * 64 + mt * 16 + l15) * Cn + kk);
#pragma unroll
        for (int nt = 0; nt < 4; ++nt)
            bb[nt] = *(const frag8*)(xb + (size_t)(nt * 16 + l15) * Cn + kk);
#pragma unroll
        for (int mt = 0; mt < 4; ++mt)
#pragma unroll
            for (int nt = 0; nt < 4; ++nt)
                acc[mt][nt] = __builtin_amdgcn_mfma_f32_16x16x32_bf16(a[mt], bb[nt], acc[mt][nt], 0, 0, 0);
    }
    u16* qtb = qt + ((size_t)(b * Nn + n0)) * Cn;
#pragma unroll
    for (int mt = 0; mt < 4; ++mt) {
        int obase = wave * 64 + mt * 16 + q4 * 4;
        float b0 = qb[obase + 0], b1 = qb[obase + 1], b2 = qb[obase + 2], b3 = qb[obase + 3];
#pragma unroll
        for (int nt = 0; nt < 4; ++nt) {
            int n = nt * 16 + l15;
            u16x4 pk;
            pk[0] = f2b(acc[mt][nt][0] + b0);
            pk[1] = f2b(acc[mt][nt][1] + b1);
            pk[2] = f2b(acc[mt][nt][2] + b2);
            pk[3] = f2b(acc[mt][nt][3] + b3);
            *(u16x4*)(qtb + (size_t)n * Cn + obase) = pk;
        }
    }
}

// ---------------- 5: fused attention (1 wave / block, NT=16 rows) ----------------
// scores^T[l][n] = sum_c k_t[l][c]*q[n][c]   (swapped QK^T: softmax needs 2 shfls)
// h_t[n][c]      = sum_l w[n][l]*v[c][l]
__launch_bounds__(64)
__global__ void k_attn(const u16* __restrict__ kt, const u16* __restrict__ v,
                       const u16* __restrict__ qt, u16* __restrict__ ht) {
    int nb = blockIdx.x, b = blockIdx.y;
    int lane = threadIdx.x;
    int l15 = lane & 15, q4 = lane >> 4;
    const u16* ktb = kt + (size_t)b * LPn * Cn;
    const u16* qtb = qt + ((size_t)(b * Nn + nb * 16)) * Cn;

    f32x4 s[5];
#pragma unroll
    for (int mt = 0; mt < 5; ++mt) s[mt] = (f32x4){0.f, 0.f, 0.f, 0.f};
#pragma unroll
    for (int ks = 0; ks < 8; ++ks) {
        int kk = ks * 32 + 8 * q4;
        frag8 bq = *(const frag8*)(qtb + (size_t)l15 * Cn + kk);
#pragma unroll
        for (int mt = 0; mt < 5; ++mt) {
            frag8 ak = *(const frag8*)(ktb + (size_t)(mt * 16 + l15) * Cn + kk);
            s[mt] = __builtin_amdgcn_mfma_f32_16x16x32_bf16(ak, bq, s[mt], 0, 0, 0);
        }
    }
    // lane holds: n = l15 (fixed), l = mt*16 + q4*4 + r. Softmax over l per n.
    float m = -3e38f;
#pragma unroll
    for (int mt = 0; mt < 5; ++mt)
#pragma unroll
        for (int r = 0; r < 4; ++r) {
            int l = mt * 16 + q4 * 4 + r;
            if (l < Ln) m = fmaxf(m, s[mt][r]);
        }
    m = fmaxf(m, __shfl_xor(m, 16));
    m = fmaxf(m, __shfl_xor(m, 32));
    float p[5][4];
    float sum = 0.f;
#pragma unroll
    for (int mt = 0; mt < 5; ++mt)
#pragma unroll
        for (int r = 0; r < 4; ++r) {
            int l = mt * 16 + q4 * 4 + r;
            float e = (l < Ln) ? __expf(s[mt][r] - m) : 0.f;
            p[mt][r] = e;
            sum += e;
        }
    sum += __shfl_xor(sum, 16);
    sum += __shfl_xor(sum, 32);
    float inv = 1.f / sum;

    __shared__ u16 w_lds[16][104];   // [n][l padded to 96 + 8 align pad]
    u32* wz = (u32*)&w_lds[0][0];    // 16*104/2 = 832 words = 13*64
#pragma unroll
    for (int i = 0; i < 13; ++i) wz[lane + i * 64] = 0;
    __syncthreads();
#pragma unroll
    for (int mt = 0; mt < 5; ++mt)
#pragma unroll
        for (int r = 0; r < 4; ++r) {
            int l = mt * 16 + q4 * 4 + r;
            if (l < Ln) w_lds[l15][l] = f2b(p[mt][r] * inv);
        }
    __syncthreads();

    frag8 aw[3];
#pragma unroll
    for (int ks = 0; ks < 3; ++ks)
        aw[ks] = *(const frag8*)(&w_lds[l15][ks * 32 + 8 * q4]);
    const u16* vb = v + (size_t)b * Cn * LKn;
    u16* hb = ht + ((size_t)(b * Nn + nb * 16)) * Cn;
#pragma unroll
    for (int ct = 0; ct < 16; ++ct) {
        f32x4 h = (f32x4){0.f, 0.f, 0.f, 0.f};
#pragma unroll
        for (int ks = 0; ks < 3; ++ks) {
            frag8 bv = *(const frag8*)(vb + (size_t)(ct * 16 + l15) * LKn + ks * 32 + 8 * q4);
            h = __builtin_amdgcn_mfma_f32_16x16x32_bf16(aw[ks], bv, h, 0, 0, 0);
        }
#pragma unroll
        for (int r = 0; r < 4; ++r)
            hb[(size_t)(q4 * 4 + r) * Cn + ct * 16 + l15] = f2b(h[r]);
    }
}

// ---------------- 6: out projection + bias + residual -> t (bf16 [b][c][n]) ----------------
__launch_bounds__(256)
__global__ void k_outproj(const u16* __restrict__ owb, const u16* __restrict__ ht,
                          const float* __restrict__ ob, const float* __restrict__ x,
                          u16* __restrict__ t) {
    int nb = blockIdx.x, b = blockIdx.y;
    int tid = threadIdx.x;
    int wave = tid >> 6, lane = tid & 63;
    int l15 = lane & 15, q4 = lane >> 4;
    int n0 = nb * 64;
    const u16* hb = ht + ((size_t)(b * Nn + n0)) * Cn;
    f32x4 acc[4][4];
#pragma unroll
    for (int mt = 0; mt < 4; ++mt)
#pragma unroll
        for (int nt = 0; nt < 4; ++nt) acc[mt][nt] = (f32x4){0.f, 0.f, 0.f, 0.f};

    for (int ks = 0; ks < 8; ++ks) {
        int kk = ks * 32 + 8 * q4;
        frag8 a[4], bb[4];
#pragma unroll
        for (int mt = 0; mt < 4; ++mt)
            a[mt] = *(const frag8*)(owb + (size_t)(wave * 64 + mt * 16 + l15) * Cn + kk);
#pragma unroll
        for (int nt = 0; nt < 4; ++nt)
            bb[nt] = *(const frag8*)(hb + (size_t)(nt * 16 + l15) * Cn + kk);
#pragma unroll
        for (int mt = 0; mt < 4; ++mt)
#pragma unroll
            for (int nt = 0; nt < 4; ++nt)
                acc[mt][nt] = __builtin_amdgcn_mfma_f32_16x16x32_bf16(a[mt], bb[nt], acc[mt][nt], 0, 0, 0);
    }
#pragma unroll
    for (int mt = 0; mt < 4; ++mt) {
        int obase = wave * 64 + mt * 16 + q4 * 4;
#pragma unroll
        for (int r = 0; r < 4; ++r) {
            int o = obase + r;
            float bias = ob[o];
            size_t rowbase = ((size_t)(b * Cn + o)) * Nn + n0;
#pragma unroll
            for (int nt = 0; nt < 4; ++nt) {
                int n = nt * 16 + l15;
                t[rowbase + n] = f2b(acc[mt][nt][r] + bias + x[rowbase + n]);
            }
        }
    }
}

// ---------------- 7: GroupNorm partial sums ----------------
__global__ void k_gnpart(const u16* __restrict__ t, float* __restrict__ gsum,
                         float* __restrict__ gsq) {
    int nc = blockIdx.x, g = blockIdx.y, b = blockIdx.z;
    int tid = threadIdx.x;
    float s = 0.f, q = 0.f;
#pragma unroll
    for (int cc = 0; cc < 8; ++cc) {
        size_t base = ((size_t)(b * Cn + g * 8 + cc)) * Nn + nc * 512;
        u32 u = *(const u32*)(t + base + tid * 2);
        float v0 = __uint_as_float(u << 16);
        float v1 = __uint_as_float(u & 0xffff0000u);
        s += v0 + v1;
        q += v0 * v0 + v1 * v1;
    }
    for (int off = 32; off > 0; off >>= 1) {
        s += __shfl_down(s, off);
        q += __shfl_down(q, off);
    }
    __shared__ float rs[4], rq[4];
    int w = tid >> 6;
    if ((tid & 63) == 0) { rs[w] = s; rq[w] = q; }
    __syncthreads();
    if (tid == 0) {
        atomicAdd(&gsum[b * Gn + g], rs[0] + rs[1] + rs[2] + rs[3]);
        atomicAdd(&gsq[b * Gn + g], rq[0] + rq[1] + rq[2] + rq[3]);
    }
}

// ---------------- 8: GroupNorm apply + Swish ----------------
__global__ void k_gnapply(const u16* __restrict__ t, const float* __restrict__ gsum,
                          const float* __restrict__ gsq, const float* __restrict__ gamma,
                          const float* __restrict__ beta, float* __restrict__ out) {
    int i = (blockIdx.x * 256 + threadIdx.x) * 4;
    int b = i >> 20;            // / (Cn*Nn)
    int rem = i & 1048575;
    int c = rem >> 12;          // / Nn
    int g = c >> 3;
    float mean = gsum[b * Gn + g] * (1.0f / 32768.f);
    float var = gsq[b * Gn + g] * (1.0f / 32768.f) - mean * mean;
    float rstd = rsqrtf(var + 1e-5f);
    float ga = gamma[c], be = beta[c];
    u16x4 tv = *(const u16x4*)(t + i);
    f32x4 o;
#pragma unroll
    for (int j = 0; j < 4; ++j) {
        float hv = (b2f(tv[j]) - mean) * rstd * ga + be;
        o[j] = hv / (1.f + __expf(-hv));
    }
    *(f32x4*)(out + i) = o;
}

// ---------------- launcher ----------------
extern "C" void kernel_launch(void* const* d_in, const int* in_sizes, int n_in,
                              void* d_out, int out_size, void* d_ws, size_t ws_size,
                              hipStream_t stream) {
    (void)in_sizes; (void)n_in; (void)out_size; (void)ws_size;
    const float* x     = (const float*)d_in[0];
    const float* ctx   = (const float*)d_in[1];
    const float* qw    = (const float*)d_in[2];
    const float* qb    = (const float*)d_in[3];
    const float* kw    = (const float*)d_in[4];
    const float* vw    = (const float*)d_in[5];
    const float* ow    = (const float*)d_in[6];
    const float* ob    = (const float*)d_in[7];
    const float* gamma = (const float*)d_in[8];
    const float* beta  = (const float*)d_in[9];
    float* out = (float*)d_out;
    char* ws = (char*)d_ws;

    u16* xt  = (u16*)(ws + OFF_XT);
    u16* ht  = (u16*)(ws + OFF_HT);
    u16* qt  = (u16*)(ws + OFF_Q);
    u16* t   = (u16*)(ws + OFF_T);
    u16* ctxb = (u16*)(ws + OFF_CTXB);
    u16* kwb  = (u16*)(ws + OFF_KWB);
    u16* vwb  = (u16*)(ws + OFF_VWB);
    u16* kt  = (u16*)(ws + OFF_KT);
    u16* v   = (u16*)(ws + OFF_V);
    u16* qwb = (u16*)(ws + OFF_QWB);
    u16* owb = (u16*)(ws + OFF_OWB);
    float* gsum = (float*)(ws + OFF_GS);
    float* gsq  = (float*)(ws + OFF_GQ);

    hipMemsetAsync(ws + OFF_GS, 0, 4096, stream);   // gsum+gsq

    k_prep<<<1472, 256, 0, stream>>>(qw, ow, kw, vw, ctx, qwb, owb, kwb, vwb, ctxb);
    k_xt<<<dim3(64, 4, 16), 256, 0, stream>>>(x, xt);
    k_kv<<<dim3(4, Bn), 256, 0, stream>>>(kwb, vwb, ctxb, kt, v);
    k_qgemm<<<dim3(64, Bn), 256, 0, stream>>>(qwb, xt, qb, qt);
    k_attn<<<dim3(256, Bn), 64, 0, stream>>>(kt, v, qt, ht);
    k_outproj<<<dim3(64, Bn), 256, 0, stream>>>(owb, ht, ob, x, t);
    k_gnpart<<<dim3(8, Gn, Bn), 256, 0, stream>>>(t, gsum, gsq);
    k_gnapply<<<16384, 256, 0, stream>>>(t, gsum, gsq, gamma, beta, out);
}

// Round 3
// 180.098 us; speedup vs baseline: 3.0909x; 1.2747x over previous
//
#include <hip/hip_runtime.h>
#include <cstdint>
#include <cstddef>

// ---------------- problem constants ----------------
#define Bn   16
#define Cn   256
#define Nn   4096      // 16^3 spatial
#define Ln   77
#define LPn  80        // padded L rows for k_t (scores N-dim, 5 tiles of 16)
#define LKn  96        // padded L for PV K-dim (3 k-steps of 32)
#define CTXn 768
#define Gn   32

typedef unsigned short u16;
typedef unsigned int   u32;
using frag8 = __attribute__((ext_vector_type(8))) short;   // 8 x bf16 (4 VGPR)
using f32x4 = __attribute__((ext_vector_type(4))) float;
using u16x4 = __attribute__((ext_vector_type(4))) u16;

__device__ __forceinline__ float b2f(u16 b) {
    union { u32 u; float f; } v; v.u = ((u32)b) << 16; return v.f;
}
__device__ __forceinline__ u16 f2b(float f) {  // RNE f32->bf16
    union { float f; u32 u; } v; v.f = f;
    u32 u = v.u;
    return (u16)((u + 0x7fffu + ((u >> 16) & 1u)) >> 16);
}
__device__ __forceinline__ u16x4 cast4(f32x4 s) {
    u16x4 p; p[0] = f2b(s[0]); p[1] = f2b(s[1]); p[2] = f2b(s[2]); p[3] = f2b(s[3]);
    return p;
}
// async global->LDS, 16B per lane. LDS dest must be lane-linear (base + lane*16).
__device__ __forceinline__ void gl16(const u16* g, u16* l) {
    __builtin_amdgcn_global_load_lds((const __attribute__((address_space(1))) u32*)g,
                                     (__attribute__((address_space(3))) u32*)l, 16, 0, 0);
}

// ---------------- ws layout (bytes) ----------------
static const size_t OFF_XT  = 0;
static const size_t OFF_HT  = 0;                    // alias: xt dead after qgemm
static const size_t OFF_Q   = 33554432;
static const size_t OFF_T   = 33554432;             // alias: q dead after attn
static const size_t OFF_CTXB = 33554432;            // bf16 [16][80][768] (dead before qgemm)
static const size_t OFF_KWB  = 35520512;            // bf16 [256][768]
static const size_t OFF_VWB  = 35913728;            // bf16 [256][768]
static const size_t OFF_KT  = 67108864;             // bf16 [B][80][256]
static const size_t OFF_V   = 67764224;             // bf16 [B][256][96]
static const size_t OFF_QWB = 68550656;             // bf16 [256][256]
static const size_t OFF_OWB = 68681728;             // bf16 [256][256]
static const size_t OFF_GS  = 68812800;             // f32 [B][32]
static const size_t OFF_GQ  = 68814848;             // f32 [B][32]

// ---------------- 1: cast everything to bf16 (vectorized, one pass) ----------------
__global__ void k_prep(const float* __restrict__ qw, const float* __restrict__ ow,
                       const float* __restrict__ kw, const float* __restrict__ vw,
                       const float* __restrict__ ctx,
                       u16* __restrict__ qwb, u16* __restrict__ owb,
                       u16* __restrict__ kwb, u16* __restrict__ vwb,
                       u16* __restrict__ ctxb) {
    int i = blockIdx.x * 256 + threadIdx.x;        // 376832 total
    if (i < 16384) {
        *(u16x4*)(qwb + i * 4) = cast4(*(const f32x4*)(qw + i * 4));
    } else if (i < 32768) {
        int j = i - 16384;
        *(u16x4*)(owb + j * 4) = cast4(*(const f32x4*)(ow + j * 4));
    } else if (i < 81920) {
        int j = i - 32768;
        *(u16x4*)(kwb + j * 4) = cast4(*(const f32x4*)(kw + j * 4));
    } else if (i < 131072) {
        int j = i - 81920;
        *(u16x4*)(vwb + j * 4) = cast4(*(const f32x4*)(vw + j * 4));
    } else {
        int j = i - 131072;                        // 0..245759
        int e = j * 4;
        int row = e / CTXn;                        // b*80 + l
        int d = e - row * CTXn;
        int b = row / LPn, l = row - b * LPn;
        u16x4 pk;
        if (l < Ln) {
            pk = cast4(*(const f32x4*)(ctx + ((size_t)(b * Ln + l)) * CTXn + d));
        } else {
            pk[0] = 0; pk[1] = 0; pk[2] = 0; pk[3] = 0;
        }
        *(u16x4*)(ctxb + e) = pk;
    }
}

// ---------------- 2: transpose+cast x[b][c][n] -> xt[b][n][c] ----------------
__global__ void k_xt(const float* __restrict__ x, u16* __restrict__ xt) {
    int b = blockIdx.z;
    int c0 = blockIdx.y * 64, n0 = blockIdx.x * 64;
    __shared__ float tile[64][65];   // +1 pad: conflict-free column reads
    int tid = threadIdx.x;
    int tr = tid >> 4, tc4 = (tid & 15) * 4;
#pragma unroll
    for (int i = 0; i < 4; ++i) {
        int cc = tr + i * 16;
        f32x4 vv = *(const f32x4*)(x + ((size_t)(b * Cn + c0 + cc)) * Nn + n0 + tc4);
#pragma unroll
        for (int j = 0; j < 4; ++j) tile[cc][tc4 + j] = vv[j];
    }
    __syncthreads();
#pragma unroll
    for (int i = 0; i < 4; ++i) {
        int nn = tr + i * 16;
        u16x4 pk;
#pragma unroll
        for (int j = 0; j < 4; ++j) pk[j] = f2b(tile[tc4 + j][nn]);
        *(u16x4*)(xt + ((size_t)(b * Nn + n0 + nn)) * Cn + c0 + tc4) = pk;
    }
}

// ---------------- 3: k/v projections via MFMA ----------------
__launch_bounds__(256)
__global__ void k_kv(const u16* __restrict__ kwb, const u16* __restrict__ vwb,
                     const u16* __restrict__ ctxb, u16* __restrict__ kt,
                     u16* __restrict__ v) {
    int b = blockIdx.y;
    int tid = threadIdx.x;
    int wave = tid >> 6, lane = tid & 63;
    int l15 = lane & 15, q4 = lane >> 4;
    int c0 = blockIdx.x * 64 + wave * 16;
    const u16* cb = ctxb + (size_t)b * LPn * CTXn;

    f32x4 ak[5], av[5];
#pragma unroll
    for (int lt = 0; lt < 5; ++lt) {
        ak[lt] = (f32x4){0.f, 0.f, 0.f, 0.f};
        av[lt] = (f32x4){0.f, 0.f, 0.f, 0.f};
    }
    for (int ks = 0; ks < CTXn / 32; ++ks) {
        int kk = ks * 32 + 8 * q4;
        frag8 fk = *(const frag8*)(kwb + (size_t)(c0 + l15) * CTXn + kk);
        frag8 fv = *(const frag8*)(vwb + (size_t)(c0 + l15) * CTXn + kk);
#pragma unroll
        for (int lt = 0; lt < 5; ++lt) {
            frag8 fc = *(const frag8*)(cb + (size_t)(lt * 16 + l15) * CTXn + kk);
            ak[lt] = __builtin_amdgcn_mfma_f32_16x16x32_bf16(fk, fc, ak[lt], 0, 0, 0);
            av[lt] = __builtin_amdgcn_mfma_f32_16x16x32_bf16(fc, fv, av[lt], 0, 0, 0);
        }
    }
#pragma unroll
    for (int lt = 0; lt < 5; ++lt) {
        *(u16x4*)(kt + ((size_t)(b * LPn + lt * 16 + l15)) * Cn + c0 + q4 * 4) = cast4(ak[lt]);
        *(u16x4*)(v + ((size_t)(b * Cn + c0 + l15)) * LKn + lt * 16 + q4 * 4) = cast4(av[lt]);
    }
    u16x4 z; z[0] = 0; z[1] = 0; z[2] = 0; z[3] = 0;
    *(u16x4*)(v + ((size_t)(b * Cn + c0 + l15)) * LKn + 80 + q4 * 4) = z;
}

// ---------------- 4/6: LDS-staged double-buffered MFMA GEMM (m97 structure) ----------------
// A [256][256] weights (k=c contiguous), Bm [B][4096][256] activations (k=c contiguous).
// MODE 0: out[n][o] = sum_c A[o][c]*Bm[n][c] + bias[o]                     (q projection)
// MODE 1: out[o][n] = sum_c A[o][c]*Bm[n][c] + bias[o] + xres[o][n],
//         plus fused GroupNorm partial sums (operands swapped: D rows = n)
template<int MODE>
__launch_bounds__(256)
__global__ void k_gemm(const u16* __restrict__ A, const u16* __restrict__ Bm,
                       const float* __restrict__ bias, const float* __restrict__ xres,
                       u16* __restrict__ outp, float* __restrict__ gsum,
                       float* __restrict__ gsq) {
    int nb = blockIdx.x, ob = blockIdx.y, b = blockIdx.z;
    int o0 = ob * 128, n0 = nb * 128;
    int tid = threadIdx.x;
    int wave = tid >> 6, lane = tid & 63;
    int l15 = lane & 15, q4 = lane >> 4;
    int wr = wave >> 1, wc = wave & 1;

    __shared__ __align__(16) u16 sA[2][128 * 32];
    __shared__ __align__(16) u16 sB[2][128 * 32];

    const u16* Ab = A + (size_t)o0 * Cn;
    const u16* Bb = Bm + ((size_t)b * Nn + n0) * Cn;
    int rowS = tid >> 2;            // 0..63 (staging row)
    int c16 = (tid & 3) * 8;        // 16B chunk within 64B row

    auto stage = [&](int buf, int ks) {
        int kk = ks * 32;
        const u16* ga = Ab + (size_t)rowS * Cn + kk + c16;
        gl16(ga,            &sA[buf][rowS * 32 + c16]);
        gl16(ga + 64 * Cn,  &sA[buf][(rowS + 64) * 32 + c16]);
        const u16* gb = Bb + (size_t)rowS * Cn + kk + c16;
        gl16(gb,            &sB[buf][rowS * 32 + c16]);
        gl16(gb + 64 * Cn,  &sB[buf][(rowS + 64) * 32 + c16]);
    };

    f32x4 acc[4][4];
#pragma unroll
    for (int i = 0; i < 4; ++i)
#pragma unroll
        for (int j = 0; j < 4; ++j) acc[i][j] = (f32x4){0.f, 0.f, 0.f, 0.f};

    stage(0, 0);
    __syncthreads();
    int cur = 0;
    for (int ks = 0; ks < 8; ++ks) {
        if (ks < 7) stage(cur ^ 1, ks + 1);
        frag8 af[4], bf[4];
#pragma unroll
        for (int mt = 0; mt < 4; ++mt)
            af[mt] = *(const frag8*)&sA[cur][(wr * 64 + mt * 16 + l15) * 32 + q4 * 8];
#pragma unroll
        for (int nt = 0; nt < 4; ++nt)
            bf[nt] = *(const frag8*)&sB[cur][(wc * 64 + nt * 16 + l15) * 32 + q4 * 8];
        if (MODE == 0) {
#pragma unroll
            for (int mt = 0; mt < 4; ++mt)
#pragma unroll
                for (int nt = 0; nt < 4; ++nt)
                    acc[mt][nt] = __builtin_amdgcn_mfma_f32_16x16x32_bf16(af[mt], bf[nt], acc[mt][nt], 0, 0, 0);
        } else {
#pragma unroll
            for (int i = 0; i < 4; ++i)
#pragma unroll
                for (int j = 0; j < 4; ++j)
                    acc[i][j] = __builtin_amdgcn_mfma_f32_16x16x32_bf16(bf[i], af[j], acc[i][j], 0, 0, 0);
        }
        __syncthreads();
        cur ^= 1;
    }

    if (MODE == 0) {
        // D rows = o (q4*4+r), cols = n (l15). Store qt[n][o], 8B contiguous in o.
        u16* qb_ = outp + (size_t)b * Nn * Cn;
#pragma unroll
        for (int mt = 0; mt < 4; ++mt) {
            int o = o0 + wr * 64 + mt * 16 + q4 * 4;
            float b0 = bias[o], b1 = bias[o + 1], b2 = bias[o + 2], b3 = bias[o + 3];
#pragma unroll
            for (int nt = 0; nt < 4; ++nt) {
                int n = n0 + wc * 64 + nt * 16 + l15;
                u16x4 pk;
                pk[0] = f2b(acc[mt][nt][0] + b0);
                pk[1] = f2b(acc[mt][nt][1] + b1);
                pk[2] = f2b(acc[mt][nt][2] + b2);
                pk[3] = f2b(acc[mt][nt][3] + b3);
                *(u16x4*)(qb_ + (size_t)n * Cn + o) = pk;
            }
        }
    } else {
        // D rows = n (i*16+q4*4+rr), cols = o (j*16+l15). Store t[o][n], 8B contiguous in n.
#pragma unroll
        for (int j = 0; j < 4; ++j) {
            int o = o0 + wr * 64 + j * 16 + l15;
            float bv = bias[o];
            size_t rowbase = ((size_t)(b * Cn + o)) * Nn + n0 + wc * 64;
            float gs = 0.f, gq = 0.f;
#pragma unroll
            for (int i = 0; i < 4; ++i) {
                int nl = i * 16 + q4 * 4;
                f32x4 xv = *(const f32x4*)(xres + rowbase + nl);
                u16x4 pk;
#pragma unroll
                for (int rr = 0; rr < 4; ++rr) {
                    float val = acc[i][j][rr] + bv + xv[rr];
                    pk[rr] = f2b(val);
                    gs += val; gq += val * val;
                }
                *(u16x4*)(outp + rowbase + nl) = pk;
            }
            // reduce over 8-lane o-group (xor 1,2,4) then across q4 (xor 16,32)
            gs += __shfl_xor(gs, 1);  gq += __shfl_xor(gq, 1);
            gs += __shfl_xor(gs, 2);  gq += __shfl_xor(gq, 2);
            gs += __shfl_xor(gs, 4);  gq += __shfl_xor(gq, 4);
            gs += __shfl_xor(gs, 16); gq += __shfl_xor(gq, 16);
            gs += __shfl_xor(gs, 32); gq += __shfl_xor(gq, 32);
            if ((lane & 55) == 0) {   // lane 0 or 8
                int g = (o0 + wr * 64 + j * 16 + (lane & 8)) >> 3;
                atomicAdd(&gsum[b * Gn + g], gs);
                atomicAdd(&gsq[b * Gn + g], gq);
            }
        }
    }
}

// ---------------- 5: fused attention (1 wave / block, NT=16 rows) ----------------
__launch_bounds__(64)
__global__ void k_attn(const u16* __restrict__ kt, const u16* __restrict__ v,
                       const u16* __restrict__ qt, u16* __restrict__ ht) {
    int nb = blockIdx.x, b = blockIdx.y;
    int lane = threadIdx.x;
    int l15 = lane & 15, q4 = lane >> 4;
    const u16* ktb = kt + (size_t)b * LPn * Cn;
    const u16* qtb = qt + ((size_t)(b * Nn + nb * 16)) * Cn;

    f32x4 s[5];
#pragma unroll
    for (int mt = 0; mt < 5; ++mt) s[mt] = (f32x4){0.f, 0.f, 0.f, 0.f};
#pragma unroll
    for (int ks = 0; ks < 8; ++ks) {
        int kk = ks * 32 + 8 * q4;
        frag8 bq = *(const frag8*)(qtb + (size_t)l15 * Cn + kk);
#pragma unroll
        for (int mt = 0; mt < 5; ++mt) {
            frag8 ak = *(const frag8*)(ktb + (size_t)(mt * 16 + l15) * Cn + kk);
            s[mt] = __builtin_amdgcn_mfma_f32_16x16x32_bf16(ak, bq, s[mt], 0, 0, 0);
        }
    }
    float m = -3e38f;
#pragma unroll
    for (int mt = 0; mt < 5; ++mt)
#pragma unroll
        for (int r = 0; r < 4; ++r) {
            int l = mt * 16 + q4 * 4 + r;
            if (l < Ln) m = fmaxf(m, s[mt][r]);
        }
    m = fmaxf(m, __shfl_xor(m, 16));
    m = fmaxf(m, __shfl_xor(m, 32));
    float p[5][4];
    float sum = 0.f;
#pragma unroll
    for (int mt = 0; mt < 5; ++mt)
#pragma unroll
        for (int r = 0; r < 4; ++r) {
            int l = mt * 16 + q4 * 4 + r;
            float e = (l < Ln) ? __expf(s[mt][r] - m) : 0.f;
            p[mt][r] = e;
            sum += e;
        }
    sum += __shfl_xor(sum, 16);
    sum += __shfl_xor(sum, 32);
    float inv = 1.f / sum;

    __shared__ u16 w_lds[16][104];
    u32* wz = (u32*)&w_lds[0][0];
#pragma unroll
    for (int i = 0; i < 13; ++i) wz[lane + i * 64] = 0;
    __syncthreads();
#pragma unroll
    for (int mt = 0; mt < 5; ++mt)
#pragma unroll
        for (int r = 0; r < 4; ++r) {
            int l = mt * 16 + q4 * 4 + r;
            if (l < Ln) w_lds[l15][l] = f2b(p[mt][r] * inv);
        }
    __syncthreads();

    frag8 aw[3];
#pragma unroll
    for (int ks = 0; ks < 3; ++ks)
        aw[ks] = *(const frag8*)(&w_lds[l15][ks * 32 + 8 * q4]);
    const u16* vb = v + (size_t)b * Cn * LKn;
    u16* hb = ht + ((size_t)(b * Nn + nb * 16)) * Cn;
#pragma unroll
    for (int ct = 0; ct < 16; ++ct) {
        f32x4 h = (f32x4){0.f, 0.f, 0.f, 0.f};
#pragma unroll
        for (int ks = 0; ks < 3; ++ks) {
            frag8 bv = *(const frag8*)(vb + (size_t)(ct * 16 + l15) * LKn + ks * 32 + 8 * q4);
            h = __builtin_amdgcn_mfma_f32_16x16x32_bf16(aw[ks], bv, h, 0, 0, 0);
        }
#pragma unroll
        for (int r = 0; r < 4; ++r)
            hb[(size_t)(q4 * 4 + r) * Cn + ct * 16 + l15] = f2b(h[r]);
    }
}

// ---------------- 8: GroupNorm apply + Swish ----------------
__global__ void k_gnapply(const u16* __restrict__ t, const float* __restrict__ gsum,
                          const float* __restrict__ gsq, const float* __restrict__ gamma,
                          const float* __restrict__ beta, float* __restrict__ out) {
    int i = (blockIdx.x * 256 + threadIdx.x) * 4;
    int b = i >> 20;
    int rem = i & 1048575;
    int c = rem >> 12;
    int g = c >> 3;
    float mean = gsum[b * Gn + g] * (1.0f / 32768.f);
    float var = gsq[b * Gn + g] * (1.0f / 32768.f) - mean * mean;
    float rstd = rsqrtf(var + 1e-5f);
    float ga = gamma[c], be = beta[c];
    u16x4 tv = *(const u16x4*)(t + i);
    f32x4 o;
#pragma unroll
    for (int j = 0; j < 4; ++j) {
        float hv = (b2f(tv[j]) - mean) * rstd * ga + be;
        o[j] = hv / (1.f + __expf(-hv));
    }
    *(f32x4*)(out + i) = o;
}

// ---------------- launcher ----------------
extern "C" void kernel_launch(void* const* d_in, const int* in_sizes, int n_in,
                              void* d_out, int out_size, void* d_ws, size_t ws_size,
                              hipStream_t stream) {
    (void)in_sizes; (void)n_in; (void)out_size; (void)ws_size;
    const float* x     = (const float*)d_in[0];
    const float* ctx   = (const float*)d_in[1];
    const float* qw    = (const float*)d_in[2];
    const float* qb    = (const float*)d_in[3];
    const float* kw    = (const float*)d_in[4];
    const float* vw    = (const float*)d_in[5];
    const float* ow    = (const float*)d_in[6];
    const float* ob    = (const float*)d_in[7];
    const float* gamma = (const float*)d_in[8];
    const float* beta  = (const float*)d_in[9];
    float* out = (float*)d_out;
    char* ws = (char*)d_ws;

    u16* xt  = (u16*)(ws + OFF_XT);
    u16* ht  = (u16*)(ws + OFF_HT);
    u16* qt  = (u16*)(ws + OFF_Q);
    u16* t   = (u16*)(ws + OFF_T);
    u16* ctxb = (u16*)(ws + OFF_CTXB);
    u16* kwb  = (u16*)(ws + OFF_KWB);
    u16* vwb  = (u16*)(ws + OFF_VWB);
    u16* kt  = (u16*)(ws + OFF_KT);
    u16* v   = (u16*)(ws + OFF_V);
    u16* qwb = (u16*)(ws + OFF_QWB);
    u16* owb = (u16*)(ws + OFF_OWB);
    float* gsum = (float*)(ws + OFF_GS);
    float* gsq  = (float*)(ws + OFF_GQ);

    hipMemsetAsync(ws + OFF_GS, 0, 4096, stream);   // gsum+gsq

    k_prep<<<1472, 256, 0, stream>>>(qw, ow, kw, vw, ctx, qwb, owb, kwb, vwb, ctxb);
    k_xt<<<dim3(64, 4, 16), 256, 0, stream>>>(x, xt);
    k_kv<<<dim3(4, Bn), 256, 0, stream>>>(kwb, vwb, ctxb, kt, v);
    k_gemm<0><<<dim3(32, 2, Bn), 256, 0, stream>>>(qwb, xt, qb, nullptr, qt, nullptr, nullptr);
    k_attn<<<dim3(256, Bn), 64, 0, stream>>>(kt, v, qt, ht);
    k_gemm<1><<<dim3(32, 2, Bn), 256, 0, stream>>>(owb, ht, ob, x, t, gsum, gsq);
    k_gnapply<<<16384, 256, 0, stream>>>(t, gsum, gsq, gamma, beta, out);
}